// Round 1
// baseline (3705.910 us; speedup 1.0000x reference)
//
#include <hip/hip_runtime.h>

#define NG 8192
#define LN_EPS 1e-5f

// ---------------- device helpers ----------------

__device__ __forceinline__ void stage(float* dst, const float* __restrict__ src,
                                      int n, int tid, int nt) {
  for (int t = tid; t < n; t += nt) dst[t] = src[t];
}

__device__ __forceinline__ void load20(const float* __restrict__ p, float v[20]) {
  const float4* q = (const float4*)p;
#pragma unroll
  for (int t = 0; t < 5; t++) {
    float4 f = q[t];
    v[t*4+0] = f.x; v[t*4+1] = f.y; v[t*4+2] = f.z; v[t*4+3] = f.w;
  }
}

__device__ __forceinline__ void store20(float* __restrict__ p, const float v[20]) {
  float4* q = (float4*)p;
#pragma unroll
  for (int t = 0; t < 5; t++)
    q[t] = make_float4(v[t*4+0], v[t*4+1], v[t*4+2], v[t*4+3]);
}

// Given pre-activation h1[20], computes LN(relu(relu(h1)@W2+b2)@W3+b3)*g+be.
// All weight reads are wave-uniform LDS broadcasts; j-inner full unroll lets
// the compiler merge the 20 consecutive weights into ds_read_b128s.
__device__ __forceinline__ void mlp23_ln(const float* __restrict__ sm,
    int W2o, int b2o, int W3o, int b3o, int go, int beo,
    const float h1[20], float out[20]) {
  float h2[20];
#pragma unroll
  for (int j = 0; j < 20; j++) h2[j] = sm[b2o + j];
#pragma unroll
  for (int k = 0; k < 20; k++) {
    float a = fmaxf(h1[k], 0.0f);
#pragma unroll
    for (int j = 0; j < 20; j++) h2[j] += a * sm[W2o + k*20 + j];
  }
  float h3[20];
#pragma unroll
  for (int j = 0; j < 20; j++) h3[j] = sm[b3o + j];
#pragma unroll
  for (int k = 0; k < 20; k++) {
    float a = fmaxf(h2[k], 0.0f);
#pragma unroll
    for (int j = 0; j < 20; j++) h3[j] += a * sm[W3o + k*20 + j];
  }
  float mu = 0.0f;
#pragma unroll
  for (int j = 0; j < 20; j++) mu += h3[j];
  mu *= 0.05f;
  float var = 0.0f;
#pragma unroll
  for (int j = 0; j < 20; j++) { float d = h3[j] - mu; var += d * d; }
  var *= 0.05f;
  float rs = rsqrtf(var + LN_EPS);
#pragma unroll
  for (int j = 0; j < 20; j++)
    out[j] = (h3[j] - mu) * rs * sm[go + j] + sm[beo + j];
}

// ---------------- kernels ----------------

// Zero u and agg; gu tables for layer 0 are just b1 (u starts at zero).
__global__ __launch_bounds__(256) void k_prelayer(
    float* __restrict__ u, float* __restrict__ agg,
    float* __restrict__ gu_nm, float* __restrict__ gu_gp,
    const float* __restrict__ nmb1, const float* __restrict__ gpb1) {
  int t = blockIdx.x * 256 + threadIdx.x;   // exactly NG*20 threads
  int j = t % 20;
  u[t] = 0.0f;
  agg[t] = 0.0f;
  gu_nm[t] = nmb1[j];
  gu_gp[t] = gpb1[j];
}

// Node-init MLP: x(N,10) -> xs(N,20)
__global__ __launch_bounds__(256) void k_init(
    const float* __restrict__ xin, float* __restrict__ xs,
    const float* __restrict__ W1, const float* __restrict__ b1,
    const float* __restrict__ W2, const float* __restrict__ b2,
    const float* __restrict__ W3, const float* __restrict__ b3,
    const float* __restrict__ gw, const float* __restrict__ bw, int n) {
  __shared__ float sm[1100];
  int tid = threadIdx.x;
  stage(sm + 0,   W1, 200, tid, 256);
  stage(sm + 200, W2, 400, tid, 256);
  stage(sm + 600, W3, 400, tid, 256);
  if (tid < 20) {
    sm[1000+tid] = b1[tid]; sm[1020+tid] = b2[tid]; sm[1040+tid] = b3[tid];
    sm[1060+tid] = gw[tid]; sm[1080+tid] = bw[tid];
  }
  __syncthreads();
  int i = blockIdx.x * 256 + tid;
  if (i >= n) return;
  float xi[10];
  const float2* xp = (const float2*)(xin + (size_t)i * 10);
#pragma unroll
  for (int t = 0; t < 5; t++) { float2 f = xp[t]; xi[t*2] = f.x; xi[t*2+1] = f.y; }
  float h1[20];
#pragma unroll
  for (int j = 0; j < 20; j++) h1[j] = sm[1000 + j];
#pragma unroll
  for (int k = 0; k < 10; k++) {
    float a = xi[k];
#pragma unroll
    for (int j = 0; j < 20; j++) h1[j] += a * sm[k*20 + j];
  }
  float out[20];
  mlp23_ln(sm, 200, 1020, 600, 1040, 1060, 1080, h1, out);
  store20(xs + (size_t)i * 20, out);
}

// Per-layer node kernel: NodeModel update (in place) + pre-aggr MLP +
// sorted-batch segmented wave reduction + boundary-lane atomics into agg.
// u[batch] never gathered: its W1 contribution is prefolded into gu_* tables.
__global__ __launch_bounds__(256) void k_node(
    const int* __restrict__ batch, float* __restrict__ xs,
    const float* __restrict__ gu_nm, const float* __restrict__ gu_gp,
    float* __restrict__ agg,
    const float* __restrict__ nmW1, const float* __restrict__ nmW2,
    const float* __restrict__ nmW3, const float* __restrict__ nmb2,
    const float* __restrict__ nmb3, const float* __restrict__ nmg,
    const float* __restrict__ nmbe,
    const float* __restrict__ gpW1, const float* __restrict__ gpW2,
    const float* __restrict__ gpW3, const float* __restrict__ gpb2,
    const float* __restrict__ gpb3, const float* __restrict__ gpg,
    const float* __restrict__ gpbe, int n) {
  __shared__ float sm[2560];
  int tid = threadIdx.x;
  stage(sm + 0,    nmW1, 400, tid, 256);   // rows 0..19 (x part) only
  stage(sm + 400,  nmW2, 400, tid, 256);
  stage(sm + 800,  nmW3, 400, tid, 256);
  stage(sm + 1200, gpW1, 400, tid, 256);
  stage(sm + 1600, gpW2, 400, tid, 256);
  stage(sm + 2000, gpW3, 400, tid, 256);
  if (tid < 20) {
    sm[2400+tid] = nmb2[tid]; sm[2420+tid] = nmb3[tid];
    sm[2440+tid] = nmg[tid];  sm[2460+tid] = nmbe[tid];
    sm[2480+tid] = gpb2[tid]; sm[2500+tid] = gpb3[tid];
    sm[2520+tid] = gpg[tid];  sm[2540+tid] = gpbe[tid];
  }
  __syncthreads();

  int i = blockIdx.x * 256 + tid;
  int lane = tid & 63;
  bool valid = i < n;
  int ic = valid ? i : (n - 1);
  int b = batch[ic];

  float x[20];
  load20(xs + (size_t)ic * 20, x);

  // ---- NodeModel: h1 = x@W1x + (u[b]@W1u + b1)  [second term = gu_nm[b]] ----
  float h1[20];
  load20(gu_nm + (size_t)b * 20, h1);
#pragma unroll
  for (int k = 0; k < 20; k++) {
    float a = x[k];
#pragma unroll
    for (int j = 0; j < 20; j++) h1[j] += a * sm[k*20 + j];
  }
  float xn[20];
  mlp23_ln(sm, 400, 2400, 800, 2420, 2440, 2460, h1, xn);
#pragma unroll
  for (int j = 0; j < 20; j++) xn[j] += x[j];     // residual
  if (valid) store20(xs + (size_t)ic * 20, xn);

  // ---- pre-aggr MLP on updated x ----
  float p1[20];
  load20(gu_gp + (size_t)b * 20, p1);
#pragma unroll
  for (int k = 0; k < 20; k++) {
    float a = xn[k];
#pragma unroll
    for (int j = 0; j < 20; j++) p1[j] += a * sm[1200 + k*20 + j];
  }
  float pre[20];
  mlp23_ln(sm, 1600, 2480, 2000, 2500, 2520, 2540, p1, pre);

  // ---- segmented inclusive scan over the wave (batch is sorted) ----
  int bs = valid ? b : -1;
  if (!valid) {
#pragma unroll
    for (int j = 0; j < 20; j++) pre[j] = 0.0f;
  }
#pragma unroll
  for (int d = 1; d < 64; d <<= 1) {
    int ob = __shfl_up(bs, d);
    bool take = (lane >= d) && (ob == bs);
#pragma unroll
    for (int j = 0; j < 20; j++) {
      float o = __shfl_up(pre[j], d);
      if (take) pre[j] += o;
    }
  }
  int nbv = __shfl_down(bs, 1);
  bool last = (lane == 63) || (nbv != bs);
  if (last && valid) {
    float* ap = agg + (size_t)b * 20;
#pragma unroll
    for (int j = 0; j < 20; j++) atomicAdd(ap + j, pre[j]);
  }
}

// Per-layer global kernel: u update (+residual), agg re-zero, and gu tables
// for the NEXT layer (fold u_{l+1} @ W1u + b1 of next layer's nm/gp MLPs).
__global__ __launch_bounds__(256) void k_global(
    float* __restrict__ u, float* __restrict__ agg,
    float* __restrict__ gu_nm, float* __restrict__ gu_gp,
    const float* __restrict__ qW1, const float* __restrict__ qb1,
    const float* __restrict__ qW2, const float* __restrict__ qb2,
    const float* __restrict__ qW3, const float* __restrict__ qb3,
    const float* __restrict__ qg,  const float* __restrict__ qbe,
    const float* __restrict__ nmW1u, const float* __restrict__ nmb1n,
    const float* __restrict__ gpW1u, const float* __restrict__ gpb1n,
    int has_next) {
  __shared__ float sm[2540];
  int tid = threadIdx.x;
  stage(sm + 0,    qW1, 800, tid, 256);    // full (40,20): rows 0..19 agg, 20..39 u
  stage(sm + 800,  qW2, 400, tid, 256);
  stage(sm + 1200, qW3, 400, tid, 256);
  if (tid < 20) {
    sm[1600+tid] = qb1[tid]; sm[1620+tid] = qb2[tid]; sm[1640+tid] = qb3[tid];
    sm[1660+tid] = qg[tid];  sm[1680+tid] = qbe[tid];
  }
  if (has_next) {
    stage(sm + 1700, nmW1u, 400, tid, 256);
    stage(sm + 2100, gpW1u, 400, tid, 256);
    if (tid < 20) { sm[2500+tid] = nmb1n[tid]; sm[2520+tid] = gpb1n[tid]; }
  }
  __syncthreads();

  int g = blockIdx.x * 256 + tid;          // exactly NG threads
  float a[20], uu[20];
  load20(agg + (size_t)g * 20, a);
  load20(u + (size_t)g * 20, uu);
  float h1[20];
#pragma unroll
  for (int j = 0; j < 20; j++) h1[j] = sm[1600 + j];
#pragma unroll
  for (int k = 0; k < 20; k++) {
    float v = a[k];
#pragma unroll
    for (int j = 0; j < 20; j++) h1[j] += v * sm[k*20 + j];
  }
#pragma unroll
  for (int k = 0; k < 20; k++) {
    float v = uu[k];
#pragma unroll
    for (int j = 0; j < 20; j++) h1[j] += v * sm[400 + k*20 + j];
  }
  float un[20];
  mlp23_ln(sm, 800, 1620, 1200, 1640, 1660, 1680, h1, un);
#pragma unroll
  for (int j = 0; j < 20; j++) un[j] += uu[j];    // residual
  store20(u + (size_t)g * 20, un);

  float z[20];
#pragma unroll
  for (int j = 0; j < 20; j++) z[j] = 0.0f;
  store20(agg + (size_t)g * 20, z);               // ready for next layer's atomics

  if (has_next) {
    float gn[20], gg2[20];
#pragma unroll
    for (int j = 0; j < 20; j++) { gn[j] = sm[2500 + j]; gg2[j] = sm[2520 + j]; }
#pragma unroll
    for (int k = 0; k < 20; k++) {
      float v = un[k];
#pragma unroll
      for (int j = 0; j < 20; j++) {
        gn[j]  += v * sm[1700 + k*20 + j];
        gg2[j] += v * sm[2100 + k*20 + j];
      }
    }
    store20(gu_nm + (size_t)g * 20, gn);
    store20(gu_gp + (size_t)g * 20, gg2);
  }
}

// ---------------- host launcher ----------------

extern "C" void kernel_launch(void* const* d_in, const int* in_sizes, int n_in,
                              void* d_out, int out_size, void* d_ws, size_t ws_size,
                              hipStream_t stream) {
  const float* x_in  = (const float*)d_in[0];
  const int*   batch = (const int*)  d_in[1];
  const float* ni_W1 = (const float*)d_in[2];
  const float* ni_b1 = (const float*)d_in[3];
  const float* ni_W2 = (const float*)d_in[4];
  const float* ni_b2 = (const float*)d_in[5];
  const float* ni_W3 = (const float*)d_in[6];
  const float* ni_b3 = (const float*)d_in[7];
  const float* ni_g  = (const float*)d_in[8];
  const float* ni_be = (const float*)d_in[9];
  const float* nm_W1 = (const float*)d_in[10];
  const float* nm_b1 = (const float*)d_in[11];
  const float* nm_W2 = (const float*)d_in[12];
  const float* nm_b2 = (const float*)d_in[13];
  const float* nm_W3 = (const float*)d_in[14];
  const float* nm_b3 = (const float*)d_in[15];
  const float* nm_g  = (const float*)d_in[16];
  const float* nm_be = (const float*)d_in[17];
  const float* gp_W1 = (const float*)d_in[18];
  const float* gp_b1 = (const float*)d_in[19];
  const float* gp_W2 = (const float*)d_in[20];
  const float* gp_b2 = (const float*)d_in[21];
  const float* gp_W3 = (const float*)d_in[22];
  const float* gp_b3 = (const float*)d_in[23];
  const float* gp_g  = (const float*)d_in[24];
  const float* gp_be = (const float*)d_in[25];
  const float* gq_W1 = (const float*)d_in[26];
  const float* gq_b1 = (const float*)d_in[27];
  const float* gq_W2 = (const float*)d_in[28];
  const float* gq_b2 = (const float*)d_in[29];
  const float* gq_W3 = (const float*)d_in[30];
  const float* gq_b3 = (const float*)d_in[31];
  const float* gq_g  = (const float*)d_in[32];
  const float* gq_be = (const float*)d_in[33];

  const int N = in_sizes[0] / 10;          // 500000
  float* xs = (float*)d_out;               // x state lives in d_out[0 .. N*20)
  float* u  = xs + (size_t)N * 20;         // u lives in d_out tail (NG*20)

  float* agg   = (float*)d_ws;             // NG*20
  float* gu_nm = agg + NG * 20;            // NG*20
  float* gu_gp = gu_nm + NG * 20;          // NG*20

  const int L = 20;
  const int nblk = (N + 255) / 256;

  k_prelayer<<<(NG * 20) / 256, 256, 0, stream>>>(u, agg, gu_nm, gu_gp, nm_b1, gp_b1);
  k_init<<<nblk, 256, 0, stream>>>(x_in, xs, ni_W1, ni_b1, ni_W2, ni_b2,
                                   ni_W3, ni_b3, ni_g, ni_be, N);
  for (int l = 0; l < L; l++) {
    k_node<<<nblk, 256, 0, stream>>>(batch, xs, gu_nm, gu_gp, agg,
        nm_W1 + (size_t)l * 800, nm_W2 + (size_t)l * 400, nm_W3 + (size_t)l * 400,
        nm_b2 + l * 20, nm_b3 + l * 20, nm_g + l * 20, nm_be + l * 20,
        gp_W1 + (size_t)l * 800, gp_W2 + (size_t)l * 400, gp_W3 + (size_t)l * 400,
        gp_b2 + l * 20, gp_b3 + l * 20, gp_g + l * 20, gp_be + l * 20, N);
    int has_next = (l < L - 1);
    k_global<<<NG / 256, 256, 0, stream>>>(u, agg, gu_nm, gu_gp,
        gq_W1 + (size_t)l * 800, gq_b1 + l * 20,
        gq_W2 + (size_t)l * 400, gq_b2 + l * 20,
        gq_W3 + (size_t)l * 400, gq_b3 + l * 20,
        gq_g + l * 20, gq_be + l * 20,
        nm_W1 + (size_t)(l + 1) * 800 + 400, nm_b1 + (l + 1) * 20,
        gp_W1 + (size_t)(l + 1) * 800 + 400, gp_b1 + (l + 1) * 20,
        has_next);
  }
}

// Round 2
// 2330.020 us; speedup vs baseline: 1.5905x; 1.5905x over previous
//
#include <hip/hip_runtime.h>

#define NG 8192
#define LN_EPS 1e-5f

// ---------------- device helpers ----------------

__device__ __forceinline__ void load20(const float* __restrict__ p, float v[20]) {
  const float4* q = (const float4*)p;
#pragma unroll
  for (int t = 0; t < 5; t++) {
    float4 f = q[t];
    v[t*4+0] = f.x; v[t*4+1] = f.y; v[t*4+2] = f.z; v[t*4+3] = f.w;
  }
}

__device__ __forceinline__ void store20(float* __restrict__ p, const float v[20]) {
  float4* q = (float4*)p;
#pragma unroll
  for (int t = 0; t < 5; t++)
    q[t] = make_float4(v[t*4+0], v[t*4+1], v[t*4+2], v[t*4+3]);
}

// LN(relu(relu(h1)@W2+b2)@W3+b3)*g+be.
// Weights read straight from global with compile-time-constant offsets off
// __restrict__ kernel-arg pointers -> provably wave-uniform -> s_load into
// SGPRs; v_fmac takes the SGPR operand. No LDS traffic at all.
__device__ __forceinline__ void mlp23_ln(
    const float* __restrict__ W2, const float* __restrict__ b2,
    const float* __restrict__ W3, const float* __restrict__ b3,
    const float* __restrict__ g,  const float* __restrict__ be,
    const float h1[20], float out[20]) {
  float h2[20];
#pragma unroll
  for (int j = 0; j < 20; j++) h2[j] = b2[j];
#pragma unroll
  for (int k = 0; k < 20; k++) {
    float a = fmaxf(h1[k], 0.0f);
#pragma unroll
    for (int j = 0; j < 20; j++) h2[j] += a * W2[k*20 + j];
  }
  float h3[20];
#pragma unroll
  for (int j = 0; j < 20; j++) h3[j] = b3[j];
#pragma unroll
  for (int k = 0; k < 20; k++) {
    float a = fmaxf(h2[k], 0.0f);
#pragma unroll
    for (int j = 0; j < 20; j++) h3[j] += a * W3[k*20 + j];
  }
  float mu = 0.0f;
#pragma unroll
  for (int j = 0; j < 20; j++) mu += h3[j];
  mu *= 0.05f;
  float var = 0.0f;
#pragma unroll
  for (int j = 0; j < 20; j++) { float d = h3[j] - mu; var += d * d; }
  var *= 0.05f;
  float rs = rsqrtf(var + LN_EPS);
#pragma unroll
  for (int j = 0; j < 20; j++)
    out[j] = (h3[j] - mu) * rs * g[j] + be[j];
}

// ---------------- kernels ----------------

// Zero u and agg; gu tables for layer 0 are just b1 (u starts at zero).
__global__ __launch_bounds__(256) void k_prelayer(
    float* __restrict__ u, float* __restrict__ agg,
    float* __restrict__ gu_nm, float* __restrict__ gu_gp,
    const float* __restrict__ nmb1, const float* __restrict__ gpb1) {
  int t = blockIdx.x * 256 + threadIdx.x;   // exactly NG*20 threads
  int j = t % 20;
  u[t] = 0.0f;
  agg[t] = 0.0f;
  gu_nm[t] = nmb1[j];
  gu_gp[t] = gpb1[j];
}

// Node-init MLP: x(N,10) -> xs(N,20)
__global__ __launch_bounds__(256) void k_init(
    const float* __restrict__ xin, float* __restrict__ xs,
    const float* __restrict__ W1, const float* __restrict__ b1,
    const float* __restrict__ W2, const float* __restrict__ b2,
    const float* __restrict__ W3, const float* __restrict__ b3,
    const float* __restrict__ gw, const float* __restrict__ bw, int n) {
  int i = blockIdx.x * 256 + threadIdx.x;
  if (i >= n) return;
  float xi[10];
  const float2* xp = (const float2*)(xin + (size_t)i * 10);
#pragma unroll
  for (int t = 0; t < 5; t++) { float2 f = xp[t]; xi[t*2] = f.x; xi[t*2+1] = f.y; }
  float h1[20];
#pragma unroll
  for (int j = 0; j < 20; j++) h1[j] = b1[j];
#pragma unroll
  for (int k = 0; k < 10; k++) {
    float a = xi[k];
#pragma unroll
    for (int j = 0; j < 20; j++) h1[j] += a * W1[k*20 + j];
  }
  float out[20];
  mlp23_ln(W2, b2, W3, b3, gw, bw, h1, out);
  store20(xs + (size_t)i * 20, out);
}

// Per-layer node kernel: NodeModel update (in place) + pre-aggr MLP +
// sorted-batch segmented wave scan + boundary-lane atomics into agg.
// u[batch] never gathered: its W1 contribution is prefolded into gu_* tables.
__global__ __launch_bounds__(256) void k_node(
    const int* __restrict__ batch, float* __restrict__ xs,
    const float* __restrict__ gu_nm, const float* __restrict__ gu_gp,
    float* __restrict__ agg,
    const float* __restrict__ nmW1, const float* __restrict__ nmW2,
    const float* __restrict__ nmW3, const float* __restrict__ nmb2,
    const float* __restrict__ nmb3, const float* __restrict__ nmg,
    const float* __restrict__ nmbe,
    const float* __restrict__ gpW1, const float* __restrict__ gpW2,
    const float* __restrict__ gpW3, const float* __restrict__ gpb2,
    const float* __restrict__ gpb3, const float* __restrict__ gpg,
    const float* __restrict__ gpbe, int n) {
  int i = blockIdx.x * 256 + threadIdx.x;
  int lane = threadIdx.x & 63;
  bool valid = i < n;
  int ic = valid ? i : (n - 1);
  int b = batch[ic];

  float x[20];
  load20(xs + (size_t)ic * 20, x);

  // ---- NodeModel: h1 = x@W1x + (u[b]@W1u + b1)  [second term = gu_nm[b]] ----
  float h1[20];
  load20(gu_nm + (size_t)b * 20, h1);
#pragma unroll
  for (int k = 0; k < 20; k++) {
    float a = x[k];
#pragma unroll
    for (int j = 0; j < 20; j++) h1[j] += a * nmW1[k*20 + j];
  }
  float xn[20];
  mlp23_ln(nmW2, nmb2, nmW3, nmb3, nmg, nmbe, h1, xn);
#pragma unroll
  for (int j = 0; j < 20; j++) xn[j] += x[j];     // residual
  if (valid) store20(xs + (size_t)ic * 20, xn);

  // ---- pre-aggr MLP on updated x ----
  float p1[20];
  load20(gu_gp + (size_t)b * 20, p1);
#pragma unroll
  for (int k = 0; k < 20; k++) {
    float a = xn[k];
#pragma unroll
    for (int j = 0; j < 20; j++) p1[j] += a * gpW1[k*20 + j];
  }
  float pre[20];
  mlp23_ln(gpW2, gpb2, gpW3, gpb3, gpg, gpbe, p1, pre);

  // ---- segmented inclusive scan over the wave (batch is sorted) ----
  int bs = valid ? b : -1;
  if (!valid) {
#pragma unroll
    for (int j = 0; j < 20; j++) pre[j] = 0.0f;
  }
#pragma unroll
  for (int d = 1; d < 64; d <<= 1) {
    int ob = __shfl_up(bs, d);
    bool take = (lane >= d) && (ob == bs);
#pragma unroll
    for (int j = 0; j < 20; j++) {
      float o = __shfl_up(pre[j], d);
      if (take) pre[j] += o;
    }
  }
  int nbv = __shfl_down(bs, 1);
  bool last = (lane == 63) || (nbv != bs);
  if (last && valid) {
    float* ap = agg + (size_t)b * 20;
#pragma unroll
    for (int j = 0; j < 20; j++) atomicAdd(ap + j, pre[j]);
  }
}

// Per-layer global kernel: u update (+residual), agg re-zero, and gu tables
// for the NEXT layer (fold u_{l+1} @ W1u + b1 of next layer's nm/gp MLPs).
__global__ __launch_bounds__(256) void k_global(
    float* __restrict__ u, float* __restrict__ agg,
    float* __restrict__ gu_nm, float* __restrict__ gu_gp,
    const float* __restrict__ qW1, const float* __restrict__ qb1,
    const float* __restrict__ qW2, const float* __restrict__ qb2,
    const float* __restrict__ qW3, const float* __restrict__ qb3,
    const float* __restrict__ qg,  const float* __restrict__ qbe,
    const float* __restrict__ nmW1u, const float* __restrict__ nmb1n,
    const float* __restrict__ gpW1u, const float* __restrict__ gpb1n,
    int has_next) {
  int g = blockIdx.x * 256 + threadIdx.x;   // exactly NG threads
  float a[20], uu[20];
  load20(agg + (size_t)g * 20, a);
  load20(u + (size_t)g * 20, uu);
  float h1[20];
#pragma unroll
  for (int j = 0; j < 20; j++) h1[j] = qb1[j];
#pragma unroll
  for (int k = 0; k < 20; k++) {
    float v = a[k];
#pragma unroll
    for (int j = 0; j < 20; j++) h1[j] += v * qW1[k*20 + j];
  }
#pragma unroll
  for (int k = 0; k < 20; k++) {
    float v = uu[k];
#pragma unroll
    for (int j = 0; j < 20; j++) h1[j] += v * qW1[400 + k*20 + j];
  }
  float un[20];
  mlp23_ln(qW2, qb2, qW3, qb3, qg, qbe, h1, un);
#pragma unroll
  for (int j = 0; j < 20; j++) un[j] += uu[j];    // residual
  store20(u + (size_t)g * 20, un);

  float z[20];
#pragma unroll
  for (int j = 0; j < 20; j++) z[j] = 0.0f;
  store20(agg + (size_t)g * 20, z);               // ready for next layer's atomics

  if (has_next) {
    float gn[20], gg2[20];
#pragma unroll
    for (int j = 0; j < 20; j++) { gn[j] = nmb1n[j]; gg2[j] = gpb1n[j]; }
#pragma unroll
    for (int k = 0; k < 20; k++) {
      float v = un[k];
#pragma unroll
      for (int j = 0; j < 20; j++) {
        gn[j]  += v * nmW1u[k*20 + j];
        gg2[j] += v * gpW1u[k*20 + j];
      }
    }
    store20(gu_nm + (size_t)g * 20, gn);
    store20(gu_gp + (size_t)g * 20, gg2);
  }
}

// ---------------- host launcher ----------------

extern "C" void kernel_launch(void* const* d_in, const int* in_sizes, int n_in,
                              void* d_out, int out_size, void* d_ws, size_t ws_size,
                              hipStream_t stream) {
  const float* x_in  = (const float*)d_in[0];
  const int*   batch = (const int*)  d_in[1];
  const float* ni_W1 = (const float*)d_in[2];
  const float* ni_b1 = (const float*)d_in[3];
  const float* ni_W2 = (const float*)d_in[4];
  const float* ni_b2 = (const float*)d_in[5];
  const float* ni_W3 = (const float*)d_in[6];
  const float* ni_b3 = (const float*)d_in[7];
  const float* ni_g  = (const float*)d_in[8];
  const float* ni_be = (const float*)d_in[9];
  const float* nm_W1 = (const float*)d_in[10];
  const float* nm_b1 = (const float*)d_in[11];
  const float* nm_W2 = (const float*)d_in[12];
  const float* nm_b2 = (const float*)d_in[13];
  const float* nm_W3 = (const float*)d_in[14];
  const float* nm_b3 = (const float*)d_in[15];
  const float* nm_g  = (const float*)d_in[16];
  const float* nm_be = (const float*)d_in[17];
  const float* gp_W1 = (const float*)d_in[18];
  const float* gp_b1 = (const float*)d_in[19];
  const float* gp_W2 = (const float*)d_in[20];
  const float* gp_b2 = (const float*)d_in[21];
  const float* gp_W3 = (const float*)d_in[22];
  const float* gp_b3 = (const float*)d_in[23];
  const float* gp_g  = (const float*)d_in[24];
  const float* gp_be = (const float*)d_in[25];
  const float* gq_W1 = (const float*)d_in[26];
  const float* gq_b1 = (const float*)d_in[27];
  const float* gq_W2 = (const float*)d_in[28];
  const float* gq_b2 = (const float*)d_in[29];
  const float* gq_W3 = (const float*)d_in[30];
  const float* gq_b3 = (const float*)d_in[31];
  const float* gq_g  = (const float*)d_in[32];
  const float* gq_be = (const float*)d_in[33];

  const int N = in_sizes[0] / 10;          // 500000
  float* xs = (float*)d_out;               // x state lives in d_out[0 .. N*20)
  float* u  = xs + (size_t)N * 20;         // u lives in d_out tail (NG*20)

  float* agg   = (float*)d_ws;             // NG*20
  float* gu_nm = agg + NG * 20;            // NG*20
  float* gu_gp = gu_nm + NG * 20;          // NG*20

  const int L = 20;
  const int nblk = (N + 255) / 256;

  k_prelayer<<<(NG * 20) / 256, 256, 0, stream>>>(u, agg, gu_nm, gu_gp, nm_b1, gp_b1);
  k_init<<<nblk, 256, 0, stream>>>(x_in, xs, ni_W1, ni_b1, ni_W2, ni_b2,
                                   ni_W3, ni_b3, ni_g, ni_be, N);
  for (int l = 0; l < L; l++) {
    k_node<<<nblk, 256, 0, stream>>>(batch, xs, gu_nm, gu_gp, agg,
        nm_W1 + (size_t)l * 800, nm_W2 + (size_t)l * 400, nm_W3 + (size_t)l * 400,
        nm_b2 + l * 20, nm_b3 + l * 20, nm_g + l * 20, nm_be + l * 20,
        gp_W1 + (size_t)l * 800, gp_W2 + (size_t)l * 400, gp_W3 + (size_t)l * 400,
        gp_b2 + l * 20, gp_b3 + l * 20, gp_g + l * 20, gp_be + l * 20, N);
    int has_next = (l < L - 1);
    k_global<<<NG / 256, 256, 0, stream>>>(u, agg, gu_nm, gu_gp,
        gq_W1 + (size_t)l * 800, gq_b1 + l * 20,
        gq_W2 + (size_t)l * 400, gq_b2 + l * 20,
        gq_W3 + (size_t)l * 400, gq_b3 + l * 20,
        gq_g + l * 20, gq_be + l * 20,
        nm_W1 + (size_t)(l + 1) * 800 + 400, nm_b1 + (l + 1) * 20,
        gp_W1 + (size_t)(l + 1) * 800 + 400, gp_b1 + (l + 1) * 20,
        has_next);
  }
}

// Round 3
// 2046.870 us; speedup vs baseline: 1.8105x; 1.1383x over previous
//
#include <hip/hip_runtime.h>

#define NG 8192
#define LN_EPS 1e-5f

typedef float v2f __attribute__((ext_vector_type(2)));

// ---------------- device helpers ----------------

__device__ __forceinline__ void load20v(const float* __restrict__ p, v2f v[10]) {
  const float4* q = (const float4*)p;
#pragma unroll
  for (int t = 0; t < 5; t++) {
    float4 f = q[t];
    v[2*t]   = (v2f){f.x, f.y};
    v[2*t+1] = (v2f){f.z, f.w};
  }
}

__device__ __forceinline__ void store20v(float* __restrict__ p, const v2f v[10]) {
  float4* q = (float4*)p;
#pragma unroll
  for (int t = 0; t < 5; t++)
    q[t] = make_float4(v[2*t].x, v[2*t].y, v[2*t+1].x, v[2*t+1].y);
}

// compile-time k only (inside unrolled loops)
__device__ __forceinline__ float elem(const v2f* a, int k) { return a[k >> 1][k & 1]; }

// LN(relu(relu(h1)@W2+b2)@W3+b3)*g+be — single node, packed fp32 pairs.
// Weights via uniform s_load (SGPR operands to v_pk_fma_f32).
__device__ __forceinline__ void mlp23_ln1(
    const float* __restrict__ W2, const float* __restrict__ b2,
    const float* __restrict__ W3, const float* __restrict__ b3,
    const float* __restrict__ g,  const float* __restrict__ be,
    const v2f h1[10], v2f out[10]) {
  const v2f* W2v = (const v2f*)W2; const v2f* b2v = (const v2f*)b2;
  const v2f* W3v = (const v2f*)W3; const v2f* b3v = (const v2f*)b3;
  const v2f* gv  = (const v2f*)g;  const v2f* bev = (const v2f*)be;
  v2f h2[10];
#pragma unroll
  for (int j = 0; j < 10; j++) h2[j] = b2v[j];
#pragma unroll
  for (int k = 0; k < 20; k++) {
    float a = fmaxf(elem(h1, k), 0.0f); v2f av = {a, a};
#pragma unroll
    for (int j = 0; j < 10; j++) h2[j] += av * W2v[k*10 + j];
  }
  v2f h3[10];
#pragma unroll
  for (int j = 0; j < 10; j++) h3[j] = b3v[j];
#pragma unroll
  for (int k = 0; k < 20; k++) {
    float a = fmaxf(elem(h2, k), 0.0f); v2f av = {a, a};
#pragma unroll
    for (int j = 0; j < 10; j++) h3[j] += av * W3v[k*10 + j];
  }
  float mu = 0.0f;
#pragma unroll
  for (int j = 0; j < 10; j++) mu += h3[j].x + h3[j].y;
  mu *= 0.05f;
  float var = 0.0f;
#pragma unroll
  for (int j = 0; j < 10; j++) {
    float dx = h3[j].x - mu, dy = h3[j].y - mu;
    var += dx*dx + dy*dy;
  }
  var *= 0.05f;
  float rs = rsqrtf(var + LN_EPS);
  v2f muv = {mu, mu}, rsv = {rs, rs};
#pragma unroll
  for (int j = 0; j < 10; j++) out[j] = (h3[j] - muv) * rsv * gv[j] + bev[j];
}

// Dual-node variant: one weight fetch feeds two independent FMA chains.
__device__ __forceinline__ void mlp23_ln2(
    const float* __restrict__ W2, const float* __restrict__ b2,
    const float* __restrict__ W3, const float* __restrict__ b3,
    const float* __restrict__ g,  const float* __restrict__ be,
    const v2f h1a[10], const v2f h1b[10], v2f outa[10], v2f outb[10]) {
  const v2f* W2v = (const v2f*)W2; const v2f* b2v = (const v2f*)b2;
  const v2f* W3v = (const v2f*)W3; const v2f* b3v = (const v2f*)b3;
  const v2f* gv  = (const v2f*)g;  const v2f* bev = (const v2f*)be;
  v2f h2a[10], h2b[10];
#pragma unroll
  for (int j = 0; j < 10; j++) { h2a[j] = b2v[j]; h2b[j] = b2v[j]; }
#pragma unroll
  for (int k = 0; k < 20; k++) {
    float aa = fmaxf(elem(h1a, k), 0.0f), ab = fmaxf(elem(h1b, k), 0.0f);
    v2f va = {aa, aa}, vb = {ab, ab};
#pragma unroll
    for (int j = 0; j < 10; j++) {
      v2f w = W2v[k*10 + j];
      h2a[j] += va * w; h2b[j] += vb * w;
    }
  }
  v2f h3a[10], h3b[10];
#pragma unroll
  for (int j = 0; j < 10; j++) { h3a[j] = b3v[j]; h3b[j] = b3v[j]; }
#pragma unroll
  for (int k = 0; k < 20; k++) {
    float aa = fmaxf(elem(h2a, k), 0.0f), ab = fmaxf(elem(h2b, k), 0.0f);
    v2f va = {aa, aa}, vb = {ab, ab};
#pragma unroll
    for (int j = 0; j < 10; j++) {
      v2f w = W3v[k*10 + j];
      h3a[j] += va * w; h3b[j] += vb * w;
    }
  }
  float mua = 0.0f, mub = 0.0f;
#pragma unroll
  for (int j = 0; j < 10; j++) {
    mua += h3a[j].x + h3a[j].y;
    mub += h3b[j].x + h3b[j].y;
  }
  mua *= 0.05f; mub *= 0.05f;
  float vara = 0.0f, varb = 0.0f;
#pragma unroll
  for (int j = 0; j < 10; j++) {
    float dx = h3a[j].x - mua, dy = h3a[j].y - mua; vara += dx*dx + dy*dy;
    float ex = h3b[j].x - mub, ey = h3b[j].y - mub; varb += ex*ex + ey*ey;
  }
  vara *= 0.05f; varb *= 0.05f;
  float rsa = rsqrtf(vara + LN_EPS), rsb = rsqrtf(varb + LN_EPS);
  v2f mva = {mua, mua}, rva = {rsa, rsa};
  v2f mvb = {mub, mub}, rvb = {rsb, rsb};
#pragma unroll
  for (int j = 0; j < 10; j++) {
    v2f gj = gv[j], bj = bev[j];
    outa[j] = (h3a[j] - mva) * rva * gj + bj;
    outb[j] = (h3b[j] - mvb) * rvb * gj + bj;
  }
}

// ---------------- kernels ----------------

__global__ __launch_bounds__(256) void k_prelayer(
    float* __restrict__ u, float* __restrict__ agg,
    float* __restrict__ gu_nm, float* __restrict__ gu_gp,
    const float* __restrict__ nmb1, const float* __restrict__ gpb1) {
  int t = blockIdx.x * 256 + threadIdx.x;   // exactly NG*20 threads
  int j = t % 20;
  u[t] = 0.0f;
  agg[t] = 0.0f;
  gu_nm[t] = nmb1[j];
  gu_gp[t] = gpb1[j];
}

// Node-init MLP: x(N,10) -> xs(N,20)
__global__ __launch_bounds__(256) void k_init(
    const float* __restrict__ xin, float* __restrict__ xs,
    const float* __restrict__ W1, const float* __restrict__ b1,
    const float* __restrict__ W2, const float* __restrict__ b2,
    const float* __restrict__ W3, const float* __restrict__ b3,
    const float* __restrict__ gw, const float* __restrict__ bw, int n) {
  int i = blockIdx.x * 256 + threadIdx.x;
  if (i >= n) return;
  float xi[10];
  const float2* xp = (const float2*)(xin + (size_t)i * 10);
#pragma unroll
  for (int t = 0; t < 5; t++) { float2 f = xp[t]; xi[t*2] = f.x; xi[t*2+1] = f.y; }
  const v2f* W1v = (const v2f*)W1; const v2f* b1v = (const v2f*)b1;
  v2f h1[10];
#pragma unroll
  for (int j = 0; j < 10; j++) h1[j] = b1v[j];
#pragma unroll
  for (int k = 0; k < 10; k++) {
    float a = xi[k]; v2f av = {a, a};
#pragma unroll
    for (int j = 0; j < 10; j++) h1[j] += av * W1v[k*10 + j];
  }
  v2f out[10];
  mlp23_ln1(W2, b2, W3, b3, gw, bw, h1, out);
  store20v(xs + (size_t)i * 20, out);
}

// Per-layer node kernel, 2 nodes/thread:
// NodeModel update (in place) + pre-aggr MLP + sorted-batch segmented wave
// scan (128 nodes/wave) + boundary-lane atomics. Batch boundary inside a
// thread ("orphan") is flushed directly with the previous lane's scan prefix.
__global__ __launch_bounds__(256) void k_node(
    const int* __restrict__ batch, float* __restrict__ xs,
    const float* __restrict__ gu_nm, const float* __restrict__ gu_gp,
    float* __restrict__ agg,
    const float* __restrict__ nmW1, const float* __restrict__ nmW2,
    const float* __restrict__ nmW3, const float* __restrict__ nmb2,
    const float* __restrict__ nmb3, const float* __restrict__ nmg,
    const float* __restrict__ nmbe,
    const float* __restrict__ gpW1, const float* __restrict__ gpW2,
    const float* __restrict__ gpW3, const float* __restrict__ gpb2,
    const float* __restrict__ gpb3, const float* __restrict__ gpg,
    const float* __restrict__ gpbe, int n) {
  int p = blockIdx.x * 256 + threadIdx.x;
  int lane = threadIdx.x & 63;
  int i0 = 2 * p, i1 = 2 * p + 1;
  bool v0 = i0 < n, v1 = i1 < n;
  int ic0 = v0 ? i0 : (n - 1);
  int ic1 = v1 ? i1 : (n - 1);
  int b0 = batch[ic0];
  int b1 = batch[ic1];

  v2f x0[10], x1[10];
  load20v(xs + (size_t)ic0 * 20, x0);
  load20v(xs + (size_t)ic1 * 20, x1);

  // ---- NodeModel: h1 = x@W1x + gu_nm[b]  (gu = u@W1u + b1, prefolded) ----
  v2f h1a[10], h1b[10];
  load20v(gu_nm + (size_t)b0 * 20, h1a);
  load20v(gu_nm + (size_t)b1 * 20, h1b);
  const v2f* W1v = (const v2f*)nmW1;
#pragma unroll
  for (int k = 0; k < 20; k++) {
    float aa = elem(x0, k), ab = elem(x1, k);
    v2f va = {aa, aa}, vb = {ab, ab};
#pragma unroll
    for (int j = 0; j < 10; j++) {
      v2f w = W1v[k*10 + j];
      h1a[j] += va * w; h1b[j] += vb * w;
    }
  }
  v2f xna[10], xnb[10];
  mlp23_ln2(nmW2, nmb2, nmW3, nmb3, nmg, nmbe, h1a, h1b, xna, xnb);
#pragma unroll
  for (int j = 0; j < 10; j++) { xna[j] += x0[j]; xnb[j] += x1[j]; }  // residual
  if (v0) store20v(xs + (size_t)ic0 * 20, xna);
  if (v1) store20v(xs + (size_t)ic1 * 20, xnb);

  // ---- pre-aggr MLP on updated x ----
  v2f p1a[10], p1b[10];
  load20v(gu_gp + (size_t)b0 * 20, p1a);
  load20v(gu_gp + (size_t)b1 * 20, p1b);
  const v2f* G1v = (const v2f*)gpW1;
#pragma unroll
  for (int k = 0; k < 20; k++) {
    float aa = elem(xna, k), ab = elem(xnb, k);
    v2f va = {aa, aa}, vb = {ab, ab};
#pragma unroll
    for (int j = 0; j < 10; j++) {
      v2f w = G1v[k*10 + j];
      p1a[j] += va * w; p1b[j] += vb * w;
    }
  }
  v2f pre0[10], pre1[10];
  mlp23_ln2(gpW2, gpb2, gpW3, gpb3, gpg, gpbe, p1a, p1b, pre0, pre1);

  // ---- segmented scan over the wave (keys sorted; 128 nodes/wave) ----
  // key = batch of this thread's LAST valid node; val excludes pre0 when the
  // pair straddles a batch boundary (orphan flushes pre0 separately).
  int key = v1 ? b1 : (v0 ? b0 : -1);
  int sb0 = v0 ? b0 : -1;                  // incoming-run id of this lane
  bool orph = v0 && v1 && (b0 != b1);
  v2f val[10];
#pragma unroll
  for (int j = 0; j < 10; j++) {
    v2f s = (v2f){0.0f, 0.0f};
    if (v0 && v1) s = (b0 == b1) ? (pre0[j] + pre1[j]) : pre1[j];
    else if (v0)  s = pre0[j];
    val[j] = s;
  }
#pragma unroll
  for (int d = 1; d < 64; d <<= 1) {
    int ok = __shfl_up(key, d);
    bool take = (lane >= d) && (ok == key);
#pragma unroll
    for (int j = 0; j < 10; j++) {
      float ox = __shfl_up(val[j].x, d);
      float oy = __shfl_up(val[j].y, d);
      if (take) { val[j].x += ox; val[j].y += oy; }
    }
  }

  // orphan flush: pre0 + (prefix of b0's run from previous lanes)
  int kprev = __shfl_up(key, 1);
  v2f sp[10];
#pragma unroll
  for (int j = 0; j < 10; j++) {
    sp[j].x = __shfl_up(val[j].x, 1);
    sp[j].y = __shfl_up(val[j].y, 1);
  }
  if (orph) {
    bool usep = (lane > 0) && (kprev == b0);
    float* ap = agg + (size_t)b0 * 20;
#pragma unroll
    for (int j = 0; j < 10; j++) {
      float ax = pre0[j].x + (usep ? sp[j].x : 0.0f);
      float ay = pre0[j].y + (usep ? sp[j].y : 0.0f);
      atomicAdd(ap + 2*j,     ax);
      atomicAdd(ap + 2*j + 1, ay);
    }
  }

  // run-end flush: run continues into lane+1 iff that lane's FIRST node
  // has the same batch.
  int nb0 = __shfl_down(sb0, 1);
  bool runend = (key >= 0) && ((lane == 63) || (nb0 != key));
  if (runend) {
    float* ap = agg + (size_t)key * 20;
#pragma unroll
    for (int j = 0; j < 10; j++) {
      atomicAdd(ap + 2*j,     val[j].x);
      atomicAdd(ap + 2*j + 1, val[j].y);
    }
  }
}

// Per-layer global kernel: u update (+residual), agg re-zero, gu tables for
// the NEXT layer.
__global__ __launch_bounds__(256) void k_global(
    float* __restrict__ u, float* __restrict__ agg,
    float* __restrict__ gu_nm, float* __restrict__ gu_gp,
    const float* __restrict__ qW1, const float* __restrict__ qb1,
    const float* __restrict__ qW2, const float* __restrict__ qb2,
    const float* __restrict__ qW3, const float* __restrict__ qb3,
    const float* __restrict__ qg,  const float* __restrict__ qbe,
    const float* __restrict__ nmW1u, const float* __restrict__ nmb1n,
    const float* __restrict__ gpW1u, const float* __restrict__ gpb1n,
    int has_next) {
  int g = blockIdx.x * 256 + threadIdx.x;   // exactly NG threads
  v2f a[10], uu[10];
  load20v(agg + (size_t)g * 20, a);
  load20v(u + (size_t)g * 20, uu);
  const v2f* qW1v = (const v2f*)qW1; const v2f* qb1v = (const v2f*)qb1;
  v2f h1[10];
#pragma unroll
  for (int j = 0; j < 10; j++) h1[j] = qb1v[j];
#pragma unroll
  for (int k = 0; k < 20; k++) {
    float v = elem(a, k); v2f av = {v, v};
#pragma unroll
    for (int j = 0; j < 10; j++) h1[j] += av * qW1v[k*10 + j];
  }
#pragma unroll
  for (int k = 0; k < 20; k++) {
    float v = elem(uu, k); v2f av = {v, v};
#pragma unroll
    for (int j = 0; j < 10; j++) h1[j] += av * qW1v[200 + k*10 + j];
  }
  v2f un[10];
  mlp23_ln1(qW2, qb2, qW3, qb3, qg, qbe, h1, un);
#pragma unroll
  for (int j = 0; j < 10; j++) un[j] += uu[j];    // residual
  store20v(u + (size_t)g * 20, un);

  v2f z[10];
#pragma unroll
  for (int j = 0; j < 10; j++) z[j] = (v2f){0.0f, 0.0f};
  store20v(agg + (size_t)g * 20, z);              // ready for next layer

  if (has_next) {
    const v2f* nW = (const v2f*)nmW1u; const v2f* nb = (const v2f*)nmb1n;
    const v2f* gW = (const v2f*)gpW1u; const v2f* gb = (const v2f*)gpb1n;
    v2f gn[10], gg2[10];
#pragma unroll
    for (int j = 0; j < 10; j++) { gn[j] = nb[j]; gg2[j] = gb[j]; }
#pragma unroll
    for (int k = 0; k < 20; k++) {
      float v = elem(un, k); v2f av = {v, v};
#pragma unroll
      for (int j = 0; j < 10; j++) {
        gn[j]  += av * nW[k*10 + j];
        gg2[j] += av * gW[k*10 + j];
      }
    }
    store20v(gu_nm + (size_t)g * 20, gn);
    store20v(gu_gp + (size_t)g * 20, gg2);
  }
}

// ---------------- host launcher ----------------

extern "C" void kernel_launch(void* const* d_in, const int* in_sizes, int n_in,
                              void* d_out, int out_size, void* d_ws, size_t ws_size,
                              hipStream_t stream) {
  const float* x_in  = (const float*)d_in[0];
  const int*   batch = (const int*)  d_in[1];
  const float* ni_W1 = (const float*)d_in[2];
  const float* ni_b1 = (const float*)d_in[3];
  const float* ni_W2 = (const float*)d_in[4];
  const float* ni_b2 = (const float*)d_in[5];
  const float* ni_W3 = (const float*)d_in[6];
  const float* ni_b3 = (const float*)d_in[7];
  const float* ni_g  = (const float*)d_in[8];
  const float* ni_be = (const float*)d_in[9];
  const float* nm_W1 = (const float*)d_in[10];
  const float* nm_b1 = (const float*)d_in[11];
  const float* nm_W2 = (const float*)d_in[12];
  const float* nm_b2 = (const float*)d_in[13];
  const float* nm_W3 = (const float*)d_in[14];
  const float* nm_b3 = (const float*)d_in[15];
  const float* nm_g  = (const float*)d_in[16];
  const float* nm_be = (const float*)d_in[17];
  const float* gp_W1 = (const float*)d_in[18];
  const float* gp_b1 = (const float*)d_in[19];
  const float* gp_W2 = (const float*)d_in[20];
  const float* gp_b2 = (const float*)d_in[21];
  const float* gp_W3 = (const float*)d_in[22];
  const float* gp_b3 = (const float*)d_in[23];
  const float* gp_g  = (const float*)d_in[24];
  const float* gp_be = (const float*)d_in[25];
  const float* gq_W1 = (const float*)d_in[26];
  const float* gq_b1 = (const float*)d_in[27];
  const float* gq_W2 = (const float*)d_in[28];
  const float* gq_b2 = (const float*)d_in[29];
  const float* gq_W3 = (const float*)d_in[30];
  const float* gq_b3 = (const float*)d_in[31];
  const float* gq_g  = (const float*)d_in[32];
  const float* gq_be = (const float*)d_in[33];

  const int N = in_sizes[0] / 10;          // 500000
  float* xs = (float*)d_out;               // x state in d_out[0 .. N*20)
  float* u  = xs + (size_t)N * 20;         // u in d_out tail (NG*20)

  float* agg   = (float*)d_ws;             // NG*20
  float* gu_nm = agg + NG * 20;            // NG*20
  float* gu_gp = gu_nm + NG * 20;          // NG*20

  const int L = 20;
  const int nblk  = (N + 255) / 256;
  const int npair = (N + 1) / 2;
  const int nblkp = (npair + 255) / 256;

  k_prelayer<<<(NG * 20) / 256, 256, 0, stream>>>(u, agg, gu_nm, gu_gp, nm_b1, gp_b1);
  k_init<<<nblk, 256, 0, stream>>>(x_in, xs, ni_W1, ni_b1, ni_W2, ni_b2,
                                   ni_W3, ni_b3, ni_g, ni_be, N);
  for (int l = 0; l < L; l++) {
    k_node<<<nblkp, 256, 0, stream>>>(batch, xs, gu_nm, gu_gp, agg,
        nm_W1 + (size_t)l * 800, nm_W2 + (size_t)l * 400, nm_W3 + (size_t)l * 400,
        nm_b2 + l * 20, nm_b3 + l * 20, nm_g + l * 20, nm_be + l * 20,
        gp_W1 + (size_t)l * 800, gp_W2 + (size_t)l * 400, gp_W3 + (size_t)l * 400,
        gp_b2 + l * 20, gp_b3 + l * 20, gp_g + l * 20, gp_be + l * 20, N);
    int has_next = (l < L - 1);
    k_global<<<NG / 256, 256, 0, stream>>>(u, agg, gu_nm, gu_gp,
        gq_W1 + (size_t)l * 800, gq_b1 + l * 20,
        gq_W2 + (size_t)l * 400, gq_b2 + l * 20,
        gq_W3 + (size_t)l * 400, gq_b3 + l * 20,
        gq_g + l * 20, gq_be + l * 20,
        nm_W1 + (size_t)(l + 1) * 800 + 400, nm_b1 + (l + 1) * 20,
        gp_W1 + (size_t)(l + 1) * 800 + 400, gp_b1 + (l + 1) * 20,
        has_next);
  }
}

// Round 4
// 1786.464 us; speedup vs baseline: 2.0744x; 1.1458x over previous
//
#include <hip/hip_runtime.h>

#define NG 8192
#define LN_EPS 1e-5f

typedef float v2f __attribute__((ext_vector_type(2)));

// ---------------- device helpers ----------------

__device__ __forceinline__ void load20v(const float* __restrict__ p, v2f v[10]) {
  const float4* q = (const float4*)p;
#pragma unroll
  for (int t = 0; t < 5; t++) {
    float4 f = q[t];
    v[2*t]   = (v2f){f.x, f.y};
    v[2*t+1] = (v2f){f.z, f.w};
  }
}

__device__ __forceinline__ void store20v(float* __restrict__ p, const v2f v[10]) {
  float4* q = (float4*)p;
#pragma unroll
  for (int t = 0; t < 5; t++)
    q[t] = make_float4(v[2*t].x, v[2*t].y, v[2*t+1].x, v[2*t+1].y);
}

// compile-time k only (inside unrolled loops)
__device__ __forceinline__ float elem(const v2f* a, int k) { return a[k >> 1][k & 1]; }

// LN(relu(relu(h1)@W2+b2)@W3+b3)*g+be — packed fp32 pairs.
// Weights via uniform s_load (SGPR operands to v_pk_fma_f32); no LDS.
__device__ __forceinline__ void mlp23_ln1(
    const float* __restrict__ W2, const float* __restrict__ b2,
    const float* __restrict__ W3, const float* __restrict__ b3,
    const float* __restrict__ g,  const float* __restrict__ be,
    const v2f h1[10], v2f out[10]) {
  const v2f* W2v = (const v2f*)W2; const v2f* b2v = (const v2f*)b2;
  const v2f* W3v = (const v2f*)W3; const v2f* b3v = (const v2f*)b3;
  const v2f* gv  = (const v2f*)g;  const v2f* bev = (const v2f*)be;
  v2f h2[10];
#pragma unroll
  for (int j = 0; j < 10; j++) h2[j] = b2v[j];
#pragma unroll
  for (int k = 0; k < 20; k++) {
    float a = fmaxf(elem(h1, k), 0.0f); v2f av = {a, a};
#pragma unroll
    for (int j = 0; j < 10; j++) h2[j] += av * W2v[k*10 + j];
  }
  v2f h3[10];
#pragma unroll
  for (int j = 0; j < 10; j++) h3[j] = b3v[j];
#pragma unroll
  for (int k = 0; k < 20; k++) {
    float a = fmaxf(elem(h2, k), 0.0f); v2f av = {a, a};
#pragma unroll
    for (int j = 0; j < 10; j++) h3[j] += av * W3v[k*10 + j];
  }
  float mu = 0.0f;
#pragma unroll
  for (int j = 0; j < 10; j++) mu += h3[j].x + h3[j].y;
  mu *= 0.05f;
  float var = 0.0f;
#pragma unroll
  for (int j = 0; j < 10; j++) {
    float dx = h3[j].x - mu, dy = h3[j].y - mu;
    var += dx*dx + dy*dy;
  }
  var *= 0.05f;
  float rs = rsqrtf(var + LN_EPS);
  v2f muv = {mu, mu}, rsv = {rs, rs};
#pragma unroll
  for (int j = 0; j < 10; j++) out[j] = (h3[j] - muv) * rsv * gv[j] + bev[j];
}

// ---------------- kernels ----------------

__global__ __launch_bounds__(256) void k_prelayer(
    float* __restrict__ u, float* __restrict__ agg,
    float* __restrict__ gu_nm, float* __restrict__ gu_gp,
    const float* __restrict__ nmb1, const float* __restrict__ gpb1) {
  int t = blockIdx.x * 256 + threadIdx.x;   // exactly NG*20 threads
  int j = t % 20;
  u[t] = 0.0f;
  agg[t] = 0.0f;
  gu_nm[t] = nmb1[j];
  gu_gp[t] = gpb1[j];
}

// Node-init MLP: x(N,10) -> xs(N,20)
__global__ __launch_bounds__(256) void k_init(
    const float* __restrict__ xin, float* __restrict__ xs,
    const float* __restrict__ W1, const float* __restrict__ b1,
    const float* __restrict__ W2, const float* __restrict__ b2,
    const float* __restrict__ W3, const float* __restrict__ b3,
    const float* __restrict__ gw, const float* __restrict__ bw, int n) {
  int i = blockIdx.x * 256 + threadIdx.x;
  if (i >= n) return;
  float xi[10];
  const float2* xp = (const float2*)(xin + (size_t)i * 10);
#pragma unroll
  for (int t = 0; t < 5; t++) { float2 f = xp[t]; xi[t*2] = f.x; xi[t*2+1] = f.y; }
  const v2f* W1v = (const v2f*)W1; const v2f* b1v = (const v2f*)b1;
  v2f h1[10];
#pragma unroll
  for (int j = 0; j < 10; j++) h1[j] = b1v[j];
#pragma unroll
  for (int k = 0; k < 10; k++) {
    float a = xi[k]; v2f av = {a, a};
#pragma unroll
    for (int j = 0; j < 10; j++) h1[j] += av * W1v[k*10 + j];
  }
  v2f out[10];
  mlp23_ln1(W2, b2, W3, b3, gw, bw, h1, out);
  store20v(xs + (size_t)i * 20, out);
}

// Per-layer node kernel, 1 node/thread (max waves for latency hiding) with
// packed-fp32 math. NodeModel update (in place) + pre-aggr MLP + sorted-batch
// segmented wave scan + run-boundary atomics into agg.
// u[batch] never gathered: its W1 contribution is prefolded into gu_* tables.
__global__ __launch_bounds__(256) void k_node(
    const int* __restrict__ batch, float* __restrict__ xs,
    const float* __restrict__ gu_nm, const float* __restrict__ gu_gp,
    float* __restrict__ agg,
    const float* __restrict__ nmW1, const float* __restrict__ nmW2,
    const float* __restrict__ nmW3, const float* __restrict__ nmb2,
    const float* __restrict__ nmb3, const float* __restrict__ nmg,
    const float* __restrict__ nmbe,
    const float* __restrict__ gpW1, const float* __restrict__ gpW2,
    const float* __restrict__ gpW3, const float* __restrict__ gpb2,
    const float* __restrict__ gpb3, const float* __restrict__ gpg,
    const float* __restrict__ gpbe, int n) {
  int i = blockIdx.x * 256 + threadIdx.x;
  int lane = threadIdx.x & 63;
  bool valid = i < n;
  int ic = valid ? i : (n - 1);
  int b = batch[ic];

  v2f x[10];
  load20v(xs + (size_t)ic * 20, x);

  // ---- NodeModel: h1 = x@W1x + gu_nm[b]  (gu = u@W1u + b1, prefolded) ----
  v2f h1[10];
  load20v(gu_nm + (size_t)b * 20, h1);
  const v2f* W1v = (const v2f*)nmW1;
#pragma unroll
  for (int k = 0; k < 20; k++) {
    float a = elem(x, k); v2f av = {a, a};
#pragma unroll
    for (int j = 0; j < 10; j++) h1[j] += av * W1v[k*10 + j];
  }
  v2f xn[10];
  mlp23_ln1(nmW2, nmb2, nmW3, nmb3, nmg, nmbe, h1, xn);
#pragma unroll
  for (int j = 0; j < 10; j++) xn[j] += x[j];     // residual
  if (valid) store20v(xs + (size_t)ic * 20, xn);

  // ---- pre-aggr MLP on updated x ----
  v2f p1[10];
  load20v(gu_gp + (size_t)b * 20, p1);
  const v2f* G1v = (const v2f*)gpW1;
#pragma unroll
  for (int k = 0; k < 20; k++) {
    float a = elem(xn, k); v2f av = {a, a};
#pragma unroll
    for (int j = 0; j < 10; j++) p1[j] += av * G1v[k*10 + j];
  }
  v2f pre[10];
  mlp23_ln1(gpW2, gpb2, gpW3, gpb3, gpg, gpbe, p1, pre);

  // ---- segmented inclusive scan over the wave (batch sorted) ----
  int key = valid ? b : -1;
  if (!valid) {
#pragma unroll
    for (int j = 0; j < 10; j++) pre[j] = (v2f){0.0f, 0.0f};
  }
#pragma unroll
  for (int d = 1; d < 64; d <<= 1) {
    int ok = __shfl_up(key, d);
    bool take = (lane >= d) && (ok == key);
#pragma unroll
    for (int j = 0; j < 10; j++) {
      float ox = __shfl_up(pre[j].x, d);
      float oy = __shfl_up(pre[j].y, d);
      if (take) { pre[j].x += ox; pre[j].y += oy; }
    }
  }
  int nbv = __shfl_down(key, 1);
  bool last = valid && ((lane == 63) || (nbv != key));
  if (last) {
    float* ap = agg + (size_t)b * 20;
#pragma unroll
    for (int j = 0; j < 10; j++) {
      atomicAdd(ap + 2*j,     pre[j].x);
      atomicAdd(ap + 2*j + 1, pre[j].y);
    }
  }
}

// Per-layer global kernel: u update (+residual), agg re-zero, gu tables for
// the NEXT layer.
__global__ __launch_bounds__(256) void k_global(
    float* __restrict__ u, float* __restrict__ agg,
    float* __restrict__ gu_nm, float* __restrict__ gu_gp,
    const float* __restrict__ qW1, const float* __restrict__ qb1,
    const float* __restrict__ qW2, const float* __restrict__ qb2,
    const float* __restrict__ qW3, const float* __restrict__ qb3,
    const float* __restrict__ qg,  const float* __restrict__ qbe,
    const float* __restrict__ nmW1u, const float* __restrict__ nmb1n,
    const float* __restrict__ gpW1u, const float* __restrict__ gpb1n,
    int has_next) {
  int g = blockIdx.x * 256 + threadIdx.x;   // exactly NG threads
  v2f a[10], uu[10];
  load20v(agg + (size_t)g * 20, a);
  load20v(u + (size_t)g * 20, uu);
  const v2f* qW1v = (const v2f*)qW1; const v2f* qb1v = (const v2f*)qb1;
  v2f h1[10];
#pragma unroll
  for (int j = 0; j < 10; j++) h1[j] = qb1v[j];
#pragma unroll
  for (int k = 0; k < 20; k++) {
    float v = elem(a, k); v2f av = {v, v};
#pragma unroll
    for (int j = 0; j < 10; j++) h1[j] += av * qW1v[k*10 + j];
  }
#pragma unroll
  for (int k = 0; k < 20; k++) {
    float v = elem(uu, k); v2f av = {v, v};
#pragma unroll
    for (int j = 0; j < 10; j++) h1[j] += av * qW1v[200 + k*10 + j];
  }
  v2f un[10];
  mlp23_ln1(qW2, qb2, qW3, qb3, qg, qbe, h1, un);
#pragma unroll
  for (int j = 0; j < 10; j++) un[j] += uu[j];    // residual
  store20v(u + (size_t)g * 20, un);

  v2f z[10];
#pragma unroll
  for (int j = 0; j < 10; j++) z[j] = (v2f){0.0f, 0.0f};
  store20v(agg + (size_t)g * 20, z);              // ready for next layer

  if (has_next) {
    const v2f* nW = (const v2f*)nmW1u; const v2f* nb = (const v2f*)nmb1n;
    const v2f* gW = (const v2f*)gpW1u; const v2f* gb = (const v2f*)gpb1n;
    v2f gn[10], gg2[10];
#pragma unroll
    for (int j = 0; j < 10; j++) { gn[j] = nb[j]; gg2[j] = gb[j]; }
#pragma unroll
    for (int k = 0; k < 20; k++) {
      float v = elem(un, k); v2f av = {v, v};
#pragma unroll
      for (int j = 0; j < 10; j++) {
        gn[j]  += av * nW[k*10 + j];
        gg2[j] += av * gW[k*10 + j];
      }
    }
    store20v(gu_nm + (size_t)g * 20, gn);
    store20v(gu_gp + (size_t)g * 20, gg2);
  }
}

// ---------------- host launcher ----------------

extern "C" void kernel_launch(void* const* d_in, const int* in_sizes, int n_in,
                              void* d_out, int out_size, void* d_ws, size_t ws_size,
                              hipStream_t stream) {
  const float* x_in  = (const float*)d_in[0];
  const int*   batch = (const int*)  d_in[1];
  const float* ni_W1 = (const float*)d_in[2];
  const float* ni_b1 = (const float*)d_in[3];
  const float* ni_W2 = (const float*)d_in[4];
  const float* ni_b2 = (const float*)d_in[5];
  const float* ni_W3 = (const float*)d_in[6];
  const float* ni_b3 = (const float*)d_in[7];
  const float* ni_g  = (const float*)d_in[8];
  const float* ni_be = (const float*)d_in[9];
  const float* nm_W1 = (const float*)d_in[10];
  const float* nm_b1 = (const float*)d_in[11];
  const float* nm_W2 = (const float*)d_in[12];
  const float* nm_b2 = (const float*)d_in[13];
  const float* nm_W3 = (const float*)d_in[14];
  const float* nm_b3 = (const float*)d_in[15];
  const float* nm_g  = (const float*)d_in[16];
  const float* nm_be = (const float*)d_in[17];
  const float* gp_W1 = (const float*)d_in[18];
  const float* gp_b1 = (const float*)d_in[19];
  const float* gp_W2 = (const float*)d_in[20];
  const float* gp_b2 = (const float*)d_in[21];
  const float* gp_W3 = (const float*)d_in[22];
  const float* gp_b3 = (const float*)d_in[23];
  const float* gp_g  = (const float*)d_in[24];
  const float* gp_be = (const float*)d_in[25];
  const float* gq_W1 = (const float*)d_in[26];
  const float* gq_b1 = (const float*)d_in[27];
  const float* gq_W2 = (const float*)d_in[28];
  const float* gq_b2 = (const float*)d_in[29];
  const float* gq_W3 = (const float*)d_in[30];
  const float* gq_b3 = (const float*)d_in[31];
  const float* gq_g  = (const float*)d_in[32];
  const float* gq_be = (const float*)d_in[33];

  const int N = in_sizes[0] / 10;          // 500000
  float* xs = (float*)d_out;               // x state in d_out[0 .. N*20)
  float* u  = xs + (size_t)N * 20;         // u in d_out tail (NG*20)

  float* agg   = (float*)d_ws;             // NG*20
  float* gu_nm = agg + NG * 20;            // NG*20
  float* gu_gp = gu_nm + NG * 20;          // NG*20

  const int L = 20;
  const int nblk = (N + 255) / 256;

  k_prelayer<<<(NG * 20) / 256, 256, 0, stream>>>(u, agg, gu_nm, gu_gp, nm_b1, gp_b1);
  k_init<<<nblk, 256, 0, stream>>>(x_in, xs, ni_W1, ni_b1, ni_W2, ni_b2,
                                   ni_W3, ni_b3, ni_g, ni_be, N);
  for (int l = 0; l < L; l++) {
    k_node<<<nblk, 256, 0, stream>>>(batch, xs, gu_nm, gu_gp, agg,
        nm_W1 + (size_t)l * 800, nm_W2 + (size_t)l * 400, nm_W3 + (size_t)l * 400,
        nm_b2 + l * 20, nm_b3 + l * 20, nm_g + l * 20, nm_be + l * 20,
        gp_W1 + (size_t)l * 800, gp_W2 + (size_t)l * 400, gp_W3 + (size_t)l * 400,
        gp_b2 + l * 20, gp_b3 + l * 20, gp_g + l * 20, gp_be + l * 20, N);
    int has_next = (l < L - 1);
    k_global<<<NG / 256, 256, 0, stream>>>(u, agg, gu_nm, gu_gp,
        gq_W1 + (size_t)l * 800, gq_b1 + l * 20,
        gq_W2 + (size_t)l * 400, gq_b2 + l * 20,
        gq_W3 + (size_t)l * 400, gq_b3 + l * 20,
        gq_g + l * 20, gq_be + l * 20,
        nm_W1 + (size_t)(l + 1) * 800 + 400, nm_b1 + (l + 1) * 20,
        gp_W1 + (size_t)(l + 1) * 800 + 400, gp_b1 + (l + 1) * 20,
        has_next);
  }
}

// Round 6
// 1556.623 us; speedup vs baseline: 2.3807x; 1.1477x over previous
//
#include <hip/hip_runtime.h>

#define NG 8192
#define LN_EPS 1e-5f

typedef float v2f __attribute__((ext_vector_type(2)));

// ---------------- DPP wave-scan helpers (VALU-only, no LDS pipe) ----------------
// wave64 inclusive scan: row_shr 1/2/4/8 within 16-lane rows, then
// row_bcast:15 (rows 1,3) and row_bcast:31 (rows 2,3).

__device__ __forceinline__ float wscan_add(float x) {
  x += __int_as_float(__builtin_amdgcn_update_dpp(0, __float_as_int(x), 0x111, 0xF, 0xF, true));
  x += __int_as_float(__builtin_amdgcn_update_dpp(0, __float_as_int(x), 0x112, 0xF, 0xF, true));
  x += __int_as_float(__builtin_amdgcn_update_dpp(0, __float_as_int(x), 0x114, 0xF, 0xF, true));
  x += __int_as_float(__builtin_amdgcn_update_dpp(0, __float_as_int(x), 0x118, 0xF, 0xF, true));
  x += __int_as_float(__builtin_amdgcn_update_dpp(0, __float_as_int(x), 0x142, 0xA, 0xF, false));
  x += __int_as_float(__builtin_amdgcn_update_dpp(0, __float_as_int(x), 0x143, 0xC, 0xF, false));
  return x;
}

__device__ __forceinline__ int wscan_max(int x) {
  int t;
  t = __builtin_amdgcn_update_dpp(0, x, 0x111, 0xF, 0xF, true); x = max(x, t);
  t = __builtin_amdgcn_update_dpp(0, x, 0x112, 0xF, 0xF, true); x = max(x, t);
  t = __builtin_amdgcn_update_dpp(0, x, 0x114, 0xF, 0xF, true); x = max(x, t);
  t = __builtin_amdgcn_update_dpp(0, x, 0x118, 0xF, 0xF, true); x = max(x, t);
  t = __builtin_amdgcn_update_dpp(0, x, 0x142, 0xA, 0xF, false); x = max(x, t);
  t = __builtin_amdgcn_update_dpp(0, x, 0x143, 0xC, 0xF, false); x = max(x, t);
  return x;
}

// ---------------- misc helpers ----------------

__device__ __forceinline__ void load20v(const float* __restrict__ p, v2f v[10]) {
  const float4* q = (const float4*)p;
#pragma unroll
  for (int t = 0; t < 5; t++) {
    float4 f = q[t];
    v[2*t]   = (v2f){f.x, f.y};
    v[2*t+1] = (v2f){f.z, f.w};
  }
}

__device__ __forceinline__ void store20v(float* __restrict__ p, const v2f v[10]) {
  float4* q = (float4*)p;
#pragma unroll
  for (int t = 0; t < 5; t++)
    q[t] = make_float4(v[2*t].x, v[2*t].y, v[2*t+1].x, v[2*t+1].y);
}

// compile-time k only (inside unrolled loops)
__device__ __forceinline__ float elem(const v2f* a, int k) { return a[k >> 1][k & 1]; }

// LN(relu(relu(h1)@W2+b2)@W3+b3)*g+be — packed fp32 pairs, SGPR weights.
__device__ __forceinline__ void mlp23_ln1(
    const float* __restrict__ W2, const float* __restrict__ b2,
    const float* __restrict__ W3, const float* __restrict__ b3,
    const float* __restrict__ g,  const float* __restrict__ be,
    const v2f h1[10], v2f out[10]) {
  const v2f* W2v = (const v2f*)W2; const v2f* b2v = (const v2f*)b2;
  const v2f* W3v = (const v2f*)W3; const v2f* b3v = (const v2f*)b3;
  const v2f* gv  = (const v2f*)g;  const v2f* bev = (const v2f*)be;
  v2f h2[10];
#pragma unroll
  for (int j = 0; j < 10; j++) h2[j] = b2v[j];
#pragma unroll
  for (int k = 0; k < 20; k++) {
    float a = fmaxf(elem(h1, k), 0.0f); v2f av = {a, a};
#pragma unroll
    for (int j = 0; j < 10; j++) h2[j] += av * W2v[k*10 + j];
  }
  v2f h3[10];
#pragma unroll
  for (int j = 0; j < 10; j++) h3[j] = b3v[j];
#pragma unroll
  for (int k = 0; k < 20; k++) {
    float a = fmaxf(elem(h2, k), 0.0f); v2f av = {a, a};
#pragma unroll
    for (int j = 0; j < 10; j++) h3[j] += av * W3v[k*10 + j];
  }
  float mu = 0.0f;
#pragma unroll
  for (int j = 0; j < 10; j++) mu += h3[j].x + h3[j].y;
  mu *= 0.05f;
  float var = 0.0f;
#pragma unroll
  for (int j = 0; j < 10; j++) {
    float dx = h3[j].x - mu, dy = h3[j].y - mu;
    var += dx*dx + dy*dy;
  }
  var *= 0.05f;
  float rs = rsqrtf(var + LN_EPS);
  v2f muv = {mu, mu}, rsv = {rs, rs};
#pragma unroll
  for (int j = 0; j < 10; j++) out[j] = (h3[j] - muv) * rsv * gv[j] + bev[j];
}

// ---------------- kernels ----------------

// Zero u and partial slots; merged gu table (per graph: [0..19]=nm, [20..39]=gp)
// init to the respective b1 (u starts at zero).
__global__ __launch_bounds__(256) void k_prelayer(
    float* __restrict__ u, float* __restrict__ part, float* __restrict__ gu,
    const float* __restrict__ nmb1, const float* __restrict__ gpb1) {
  int t = blockIdx.x * 256 + threadIdx.x;   // NG*80 threads
  part[t] = 0.0f;
  if (t < NG * 40) {
    int j = t % 40;
    gu[t] = (j < 20) ? nmb1[j] : gpb1[j - 20];
  }
  if (t < NG * 20) u[t] = 0.0f;
}

// Node-init MLP: x(N,10) -> xs(N,20)
__global__ __launch_bounds__(256) void k_init(
    const float* __restrict__ xin, float* __restrict__ xs,
    const float* __restrict__ W1, const float* __restrict__ b1,
    const float* __restrict__ W2, const float* __restrict__ b2,
    const float* __restrict__ W3, const float* __restrict__ b3,
    const float* __restrict__ gw, const float* __restrict__ bw, int n) {
  int i = blockIdx.x * 256 + threadIdx.x;
  if (i >= n) return;
  float xi[10];
  const float2* xp = (const float2*)(xin + (size_t)i * 10);
#pragma unroll
  for (int t = 0; t < 5; t++) { float2 f = xp[t]; xi[t*2] = f.x; xi[t*2+1] = f.y; }
  const v2f* W1v = (const v2f*)W1; const v2f* b1v = (const v2f*)b1;
  v2f h1[10];
#pragma unroll
  for (int j = 0; j < 10; j++) h1[j] = b1v[j];
#pragma unroll
  for (int k = 0; k < 10; k++) {
    float a = xi[k]; v2f av = {a, a};
#pragma unroll
    for (int j = 0; j < 10; j++) h1[j] += av * W1v[k*10 + j];
  }
  v2f out[10];
  mlp23_ln1(W2, b2, W3, b3, gw, bw, h1, out);
  store20v(xs + (size_t)i * 20, out);
}

// Per-layer node kernel, 1 node/thread, pk-fp32, SGPR weights.
// Aggregation is DETERMINISTIC: DPP wave scan -> run-end lane STORES its
// partial into slot (node>>6)&3 of part[graph][4][20]. No atomics anywhere,
// so every launch is bitwise identical (sorted batch; graphs span <=4 waves).
__global__ __launch_bounds__(256) void k_node(
    const int* __restrict__ batch, float* __restrict__ xs,
    const float* __restrict__ gu, float* __restrict__ part,
    const float* __restrict__ nmW1, const float* __restrict__ nmW2,
    const float* __restrict__ nmW3, const float* __restrict__ nmb2,
    const float* __restrict__ nmb3, const float* __restrict__ nmg,
    const float* __restrict__ nmbe,
    const float* __restrict__ gpW1, const float* __restrict__ gpW2,
    const float* __restrict__ gpW3, const float* __restrict__ gpb2,
    const float* __restrict__ gpb3, const float* __restrict__ gpg,
    const float* __restrict__ gpbe, int n) {
  int i = blockIdx.x * 256 + threadIdx.x;
  int lane = threadIdx.x & 63;
  bool valid = i < n;
  int ic = valid ? i : (n - 1);
  int b = batch[ic];

  v2f x[10];
  load20v(xs + (size_t)ic * 20, x);

  // ---- NodeModel: h1 = x@W1x + gu_nm[b]  (gu = u@W1u + b1, prefolded) ----
  v2f h1[10];
  load20v(gu + (size_t)b * 40, h1);
  const v2f* W1v = (const v2f*)nmW1;
#pragma unroll
  for (int k = 0; k < 20; k++) {
    float a = elem(x, k); v2f av = {a, a};
#pragma unroll
    for (int j = 0; j < 10; j++) h1[j] += av * W1v[k*10 + j];
  }
  v2f xn[10];
  mlp23_ln1(nmW2, nmb2, nmW3, nmb3, nmg, nmbe, h1, xn);
#pragma unroll
  for (int j = 0; j < 10; j++) xn[j] += x[j];     // residual
  if (valid) store20v(xs + (size_t)ic * 20, xn);

  // ---- pre-aggr MLP on updated x ----
  v2f p1[10];
  load20v(gu + (size_t)b * 40 + 20, p1);
  const v2f* G1v = (const v2f*)gpW1;
#pragma unroll
  for (int k = 0; k < 20; k++) {
    float a = elem(xn, k); v2f av = {a, a};
#pragma unroll
    for (int j = 0; j < 10; j++) p1[j] += av * G1v[k*10 + j];
  }
  v2f pre[10];
  mlp23_ln1(gpW2, gpb2, gpW3, gpb3, gpg, gpbe, p1, pre);

  // ---- aggregation: DPP scan + run-end slot stores (batch sorted) ----
  int key = valid ? b : -1;
  if (!valid) {
#pragma unroll
    for (int j = 0; j < 10; j++) pre[j] = (v2f){0.0f, 0.0f};
  }
  // prev/next key via whole-wave DPP shifts (WAVE_SHR1 / WAVE_SHL1)
  int pk = __builtin_amdgcn_update_dpp(-1, key, 0x138, 0xF, 0xF, false);
  int nk = __builtin_amdgcn_update_dpp(-2, key, 0x130, 0xF, 0xF, false);
  bool isstart = (key != pk);
  int st = wscan_max(isstart ? lane : 0);   // start lane of my run

  // unsegmented inclusive scan of all 20 components (VALU-only)
#pragma unroll
  for (int j = 0; j < 10; j++) {
    pre[j].x = wscan_add(pre[j].x);
    pre[j].y = wscan_add(pre[j].y);
  }

  // segment sum at run-end = incl - prefix_before_start (bpermute gather)
  int pl = (st > 0) ? (st - 1) : 0;
  float use = (st > 0) ? 1.0f : 0.0f;
  v2f fl[10];
#pragma unroll
  for (int j = 0; j < 10; j++) {
    float bx = __shfl(pre[j].x, pl);
    float by = __shfl(pre[j].y, pl);
    fl[j].x = pre[j].x - use * bx;
    fl[j].y = pre[j].y - use * by;
  }
  bool runend = valid && (nk != key);       // lane63 gets nk=-2 -> true
  if (runend) {
    int slot = (i >> 6) & 3;                // graphs span <=4 consecutive waves
    float* pp = part + (size_t)b * 80 + slot * 20;
#pragma unroll
    for (int j = 0; j < 10; j++) {
      pp[2*j]     = fl[j].x;
      pp[2*j + 1] = fl[j].y;
    }
  }
}

// Per-layer global kernel (128 blocks x 64 thr, SGPR weights): sum the 4
// partial slots in FIXED order (deterministic), u update (+residual), re-zero
// slots for the next layer, write gu tables for the NEXT layer.
__global__ __launch_bounds__(64) void k_global(
    float* __restrict__ u, float* __restrict__ part, float* __restrict__ gu,
    const float* __restrict__ qW1, const float* __restrict__ qb1,
    const float* __restrict__ qW2, const float* __restrict__ qb2,
    const float* __restrict__ qW3, const float* __restrict__ qb3,
    const float* __restrict__ qg,  const float* __restrict__ qbe,
    const float* __restrict__ nmW1u, const float* __restrict__ nmb1n,
    const float* __restrict__ gpW1u, const float* __restrict__ gpb1n,
    int has_next) {
  int g = blockIdx.x * 64 + threadIdx.x;    // exactly NG threads
  float* pg = part + (size_t)g * 80;
  v2f s0[10], s1[10], s2[10], s3[10];
  load20v(pg,      s0);
  load20v(pg + 20, s1);
  load20v(pg + 40, s2);
  load20v(pg + 60, s3);
  v2f a[10];
#pragma unroll
  for (int j = 0; j < 10; j++) a[j] = ((s0[j] + s1[j]) + s2[j]) + s3[j];

  v2f uu[10];
  load20v(u + (size_t)g * 20, uu);
  const v2f* qW1v = (const v2f*)qW1; const v2f* qb1v = (const v2f*)qb1;
  v2f h1[10];
#pragma unroll
  for (int j = 0; j < 10; j++) h1[j] = qb1v[j];
#pragma unroll
  for (int k = 0; k < 20; k++) {
    float v = elem(a, k); v2f av = {v, v};
#pragma unroll
    for (int j = 0; j < 10; j++) h1[j] += av * qW1v[k*10 + j];
  }
#pragma unroll
  for (int k = 0; k < 20; k++) {
    float v = elem(uu, k); v2f av = {v, v};
#pragma unroll
    for (int j = 0; j < 10; j++) h1[j] += av * qW1v[200 + k*10 + j];
  }
  v2f un[10];
  mlp23_ln1(qW2, qb2, qW3, qb3, qg, qbe, h1, un);
#pragma unroll
  for (int j = 0; j < 10; j++) un[j] += uu[j];    // residual
  store20v(u + (size_t)g * 20, un);

  v2f z[10];
#pragma unroll
  for (int j = 0; j < 10; j++) z[j] = (v2f){0.0f, 0.0f};
  store20v(pg,      z);                            // re-zero slots for next layer
  store20v(pg + 20, z);
  store20v(pg + 40, z);
  store20v(pg + 60, z);

  if (has_next) {
    const v2f* nW = (const v2f*)nmW1u; const v2f* nb = (const v2f*)nmb1n;
    const v2f* gW = (const v2f*)gpW1u; const v2f* gb = (const v2f*)gpb1n;
    v2f gn[10], gg2[10];
#pragma unroll
    for (int j = 0; j < 10; j++) { gn[j] = nb[j]; gg2[j] = gb[j]; }
#pragma unroll
    for (int k = 0; k < 20; k++) {
      float v = elem(un, k); v2f av = {v, v};
#pragma unroll
      for (int j = 0; j < 10; j++) {
        gn[j]  += av * nW[k*10 + j];
        gg2[j] += av * gW[k*10 + j];
      }
    }
    store20v(gu + (size_t)g * 40, gn);
    store20v(gu + (size_t)g * 40 + 20, gg2);
  }
}

// ---------------- host launcher ----------------

extern "C" void kernel_launch(void* const* d_in, const int* in_sizes, int n_in,
                              void* d_out, int out_size, void* d_ws, size_t ws_size,
                              hipStream_t stream) {
  const float* x_in  = (const float*)d_in[0];
  const int*   batch = (const int*)  d_in[1];
  const float* ni_W1 = (const float*)d_in[2];
  const float* ni_b1 = (const float*)d_in[3];
  const float* ni_W2 = (const float*)d_in[4];
  const float* ni_b2 = (const float*)d_in[5];
  const float* ni_W3 = (const float*)d_in[6];
  const float* ni_b3 = (const float*)d_in[7];
  const float* ni_g  = (const float*)d_in[8];
  const float* ni_be = (const float*)d_in[9];
  const float* nm_W1 = (const float*)d_in[10];
  const float* nm_b1 = (const float*)d_in[11];
  const float* nm_W2 = (const float*)d_in[12];
  const float* nm_b2 = (const float*)d_in[13];
  const float* nm_W3 = (const float*)d_in[14];
  const float* nm_b3 = (const float*)d_in[15];
  const float* nm_g  = (const float*)d_in[16];
  const float* nm_be = (const float*)d_in[17];
  const float* gp_W1 = (const float*)d_in[18];
  const float* gp_b1 = (const float*)d_in[19];
  const float* gp_W2 = (const float*)d_in[20];
  const float* gp_b2 = (const float*)d_in[21];
  const float* gp_W3 = (const float*)d_in[22];
  const float* gp_b3 = (const float*)d_in[23];
  const float* gp_g  = (const float*)d_in[24];
  const float* gp_be = (const float*)d_in[25];
  const float* gq_W1 = (const float*)d_in[26];
  const float* gq_b1 = (const float*)d_in[27];
  const float* gq_W2 = (const float*)d_in[28];
  const float* gq_b2 = (const float*)d_in[29];
  const float* gq_W3 = (const float*)d_in[30];
  const float* gq_b3 = (const float*)d_in[31];
  const float* gq_g  = (const float*)d_in[32];
  const float* gq_be = (const float*)d_in[33];

  const int N = in_sizes[0] / 10;          // 500000
  float* xs = (float*)d_out;               // x state in d_out[0 .. N*20)
  float* u  = xs + (size_t)N * 20;         // u in d_out tail (NG*20)

  float* part = (float*)d_ws;              // NG*80 (4 slots x 20 per graph)
  float* gu   = part + NG * 80;            // NG*40 (merged nm|gp table)

  const int L = 20;
  const int nblk = (N + 255) / 256;

  k_prelayer<<<(NG * 80) / 256, 256, 0, stream>>>(u, part, gu, nm_b1, gp_b1);
  k_init<<<nblk, 256, 0, stream>>>(x_in, xs, ni_W1, ni_b1, ni_W2, ni_b2,
                                   ni_W3, ni_b3, ni_g, ni_be, N);
  for (int l = 0; l < L; l++) {
    k_node<<<nblk, 256, 0, stream>>>(batch, xs, gu, part,
        nm_W1 + (size_t)l * 800, nm_W2 + (size_t)l * 400, nm_W3 + (size_t)l * 400,
        nm_b2 + l * 20, nm_b3 + l * 20, nm_g + l * 20, nm_be + l * 20,
        gp_W1 + (size_t)l * 800, gp_W2 + (size_t)l * 400, gp_W3 + (size_t)l * 400,
        gp_b2 + l * 20, gp_b3 + l * 20, gp_g + l * 20, gp_be + l * 20, N);
    int has_next = (l < L - 1);
    k_global<<<NG / 64, 64, 0, stream>>>(u, part, gu,
        gq_W1 + (size_t)l * 800, gq_b1 + l * 20,
        gq_W2 + (size_t)l * 400, gq_b2 + l * 20,
        gq_W3 + (size_t)l * 400, gq_b3 + l * 20,
        gq_g + l * 20, gq_be + l * 20,
        nm_W1 + (size_t)(l + 1) * 800 + 400, nm_b1 + (l + 1) * 20,
        gp_W1 + (size_t)(l + 1) * 800 + 400, gp_b1 + (l + 1) * 20,
        has_next);
  }
}